// Round 3
// baseline (913.038 us; speedup 1.0000x reference)
//
#include <hip/hip_runtime.h>
#include <math.h>

#define NN 50000
#define NE 800000
#define NBK 782   // ceil(NN/64) 64-node dst buckets

typedef __bf16 bf16x8 __attribute__((ext_vector_type(8)));
typedef float  f32x4  __attribute__((ext_vector_type(4)));

__device__ __forceinline__ ushort f2b(float f) {
  union { float f; uint u; } v; v.f = f;
  uint u = v.u;
  return (ushort)((u + 0x7fffu + ((u >> 16) & 1u)) >> 16);  // RNE
}
__device__ __forceinline__ float b2f(ushort b) {
  union { uint u; float f; } v; v.u = ((uint)b) << 16;
  return v.f;
}
__device__ __forceinline__ uint4 cvt8(const float* p) {
  float4 a = *(const float4*)p, b = *(const float4*)(p + 4);
  uint4 u;
  u.x = (uint)f2b(a.x) | ((uint)f2b(a.y) << 16);
  u.y = (uint)f2b(a.z) | ((uint)f2b(a.w) << 16);
  u.z = (uint)f2b(b.x) | ((uint)f2b(b.y) << 16);
  u.w = (uint)f2b(b.z) | ((uint)f2b(b.w) << 16);
  return u;
}

// ---------------------------------------------------------------------------
// cvt_w: weights -> bf16, transposed to [n][k]
// ---------------------------------------------------------------------------
__global__ __launch_bounds__(256) void cvt_w(const float* __restrict__ Wfc,
    const float* __restrict__ Wpr, const float* __restrict__ Wgt,
    ushort* __restrict__ Tfc, ushort* __restrict__ Tpr, ushort* __restrict__ Tgt) {
  int t = blockIdx.x * 256 + threadIdx.x;
  if (t < 16384) {
    int n = t >> 7, k = t & 127;
    Tfc[n * 128 + k] = f2b(Wfc[k * 128 + n]);
  } else if (t < 32768) {
    int i = t - 16384; int n = i >> 7, k = i & 127;
    Tpr[n * 128 + k] = f2b(Wpr[k * 128 + n]);
  } else if (t < 65536) {
    int i = t - 32768; int n = i >> 8, k = i & 255;
    Tgt[n * 256 + k] = f2b(Wgt[k * 128 + n]);
  }
}

// ---------------------------------------------------------------------------
// bucket histogram: LDS-binned per block, one global atomic per bucket.
// ---------------------------------------------------------------------------
__global__ __launch_bounds__(512) void bhist(const int* __restrict__ dst,
                                             int* __restrict__ gcnt) {
  __shared__ int lcnt[NBK];
  const int tid = threadIdx.x;
  for (int i = tid; i < NBK; i += 512) lcnt[i] = 0;
  __syncthreads();
  for (int e = blockIdx.x * 512 + tid; e < NE; e += 128 * 512)
    atomicAdd(&lcnt[dst[e] >> 6], 1);
  __syncthreads();
  for (int i = tid; i < NBK; i += 512) {
    int c = lcnt[i];
    if (c) atomicAdd(&gcnt[i], c);
  }
}

// single-block exclusive scan over NBK bucket counts -> boff + gcursor
__global__ __launch_bounds__(256) void bscan(const int* __restrict__ gcnt,
                                             int* __restrict__ boff,
                                             int* __restrict__ gcursor) {
  __shared__ int ws[4];
  __shared__ int carry;
  const int tid = threadIdx.x, ln = tid & 63, wv = tid >> 6;
  if (tid == 0) carry = 0;
  __syncthreads();
  for (int base = 0; base < NBK; base += 256) {
    int i = base + tid;
    int x = (i < NBK) ? gcnt[i] : 0;
    int v = x;
#pragma unroll
    for (int d = 1; d < 64; d <<= 1) {
      int t = __shfl_up(v, d);
      if (ln >= d) v += t;
    }
    if (ln == 63) ws[wv] = v;
    __syncthreads();
    int w0 = ws[0], w1 = ws[1], w2 = ws[2], w3 = ws[3];
    int woff = (wv == 0) ? 0 : (wv == 1) ? w0 : (wv == 2) ? w0 + w1 : w0 + w1 + w2;
    int excl = carry + woff + v - x;
    if (i < NBK) { boff[i] = excl; gcursor[i] = excl; }
    int tot = w0 + w1 + w2 + w3;
    __syncthreads();
    if (tid == 0) carry += tot;
    __syncthreads();
  }
  if (threadIdx.x == 0) boff[NBK] = NE;
}

// ---------------------------------------------------------------------------
// bucket scatter: block-local LDS counts -> per-bucket range reserve ->
// packed (src<<6 | dstLow) appended. Block writes stay in a ~25KB L2-hot
// frontier (contiguous runs per bucket) -> low write amplification.
// ---------------------------------------------------------------------------
__global__ __launch_bounds__(512) void bscatter(const int* __restrict__ src,
    const int* __restrict__ dst, int* __restrict__ gcursor,
    uint* __restrict__ packed) {
  __shared__ int lcnt[NBK];
  __shared__ int lbase[NBK];
  __shared__ int lrank[NBK];
  const int tid = threadIdx.x;
  const int PER = (NE + 127) / 128;   // 6250
  const int e0 = blockIdx.x * PER;
  const int e1 = min(NE, e0 + PER);
  for (int i = tid; i < NBK; i += 512) { lcnt[i] = 0; lrank[i] = 0; }
  __syncthreads();
  for (int e = e0 + tid; e < e1; e += 512) atomicAdd(&lcnt[dst[e] >> 6], 1);
  __syncthreads();
  for (int i = tid; i < NBK; i += 512) {
    int c = lcnt[i];
    lbase[i] = c ? atomicAdd(&gcursor[i], c) : 0;
  }
  __syncthreads();
  for (int e = e0 + tid; e < e1; e += 512) {
    int d = dst[e], b = d >> 6;
    int r = atomicAdd(&lrank[b], 1);
    packed[lbase[b] + r] = ((uint)src[e] << 6) | (uint)(d & 63);
  }
}

// ---------------------------------------------------------------------------
// MFMA GEMM: out[M x 128] = A[M x K] @ Wt^T, K = KS*32.
// MODE 0: A = f32 h (staged-convert); out feat bf16 + fused el/er epilogue.
// MODE 1: A = bf16; out = A@W + bias (bf16).
// MODE 2: A0 = bf16 hp (K 0..127), A1 = f32 ctx (K 128..255, staged-convert);
//         g = sigmoid(acc + bias); out_f32 = g*hp + (1-g)*ctx (hp/ctx from LDS).
// ---------------------------------------------------------------------------
template<int KS, int MODE>
__global__ __launch_bounds__(256) void mgemm(
    const ushort* __restrict__ A0b, const float* __restrict__ A0f,
    const float* __restrict__ A1f, const ushort* __restrict__ Wt,
    const float* __restrict__ bias, const float* __restrict__ al,
    const float* __restrict__ ar, float* __restrict__ el,
    float* __restrict__ er, ushort* __restrict__ outb,
    float* __restrict__ outf, int M)
{
  constexpr int K  = KS * 32;
  constexpr int K2 = K * 2;              // bytes per LDS row
  constexpr int CPR = K2 / 16;           // 16B chunks per row
  constexpr int CHT = 128 * CPR / 256;   // chunks per thread per tile
  extern __shared__ char lds[];
  char* As = lds;
  char* Bs = lds + 128 * K2;
  const int tid  = threadIdx.x;
  const int row0 = blockIdx.x * 128;

#pragma unroll
  for (int c = 0; c < CHT; c++) {
    int idx = tid + c * 256;
    int r  = idx / CPR;
    int kc = idx % CPR;
    int sw = ((kc * 16) ^ ((r & 7) << 4));
    int grow = row0 + r;
    uint4 va = make_uint4(0u, 0u, 0u, 0u);
    if (grow < M) {
      if (MODE == 0) {
        va = cvt8(A0f + (size_t)grow * 128 + kc * 8);
      } else if (MODE == 1) {
        va = *(const uint4*)(A0b + (size_t)grow * 128 + kc * 8);
      } else {
        if (kc < CPR / 2) va = *(const uint4*)(A0b + (size_t)grow * 128 + kc * 8);
        else va = cvt8(A1f + (size_t)grow * 128 + (kc - CPR / 2) * 8);
      }
    }
    *(uint4*)(As + r * K2 + sw) = va;
    uint4 vb = *(const uint4*)(Wt + (size_t)idx * 8);
    *(uint4*)(Bs + r * K2 + sw) = vb;
  }
  __syncthreads();

  const int ln = tid & 63, wv = tid >> 6;
  const int wm = wv >> 1, wn = wv & 1;
  const int lr = ln & 15, lk = ln >> 4;

  f32x4 acc[4][4] = {};
#pragma unroll
  for (int ks = 0; ks < KS; ks++) {
    int k2 = ks * 64 + lk * 16;
    bf16x8 af[4], bfr[4];
#pragma unroll
    for (int t = 0; t < 4; t++) {
      int arr = wm * 64 + t * 16 + lr;
      af[t]  = *(const bf16x8*)(As + arr * K2 + (k2 ^ ((arr & 7) << 4)));
      int bn = wn * 64 + t * 16 + lr;
      bfr[t] = *(const bf16x8*)(Bs + bn * K2 + (k2 ^ ((bn & 7) << 4)));
    }
#pragma unroll
    for (int mt = 0; mt < 4; mt++)
#pragma unroll
      for (int nt = 0; nt < 4; nt++)
        acc[mt][nt] = __builtin_amdgcn_mfma_f32_16x16x32_bf16(
            af[mt], bfr[nt], acc[mt][nt], 0, 0, 0);
  }

  if (MODE == 0) {
    float alv[4], arv[4];
#pragma unroll
    for (int nt = 0; nt < 4; nt++) {
      int col = wn * 64 + nt * 16 + lr;
      alv[nt] = al[col]; arv[nt] = ar[col];
    }
#pragma unroll
    for (int mt = 0; mt < 4; mt++) {
#pragma unroll
      for (int r = 0; r < 4; r++) {
        int row = row0 + wm * 64 + mt * 16 + lk * 4 + r;
        float pl0 = acc[mt][0][r] * alv[0] + acc[mt][1][r] * alv[1];
        float pl1 = acc[mt][2][r] * alv[2] + acc[mt][3][r] * alv[3];
        float pr0 = acc[mt][0][r] * arv[0] + acc[mt][1][r] * arv[1];
        float pr1 = acc[mt][2][r] * arv[2] + acc[mt][3][r] * arv[3];
#pragma unroll
        for (int m2 = 1; m2 < 16; m2 <<= 1) {
          pl0 += __shfl_xor(pl0, m2); pl1 += __shfl_xor(pl1, m2);
          pr0 += __shfl_xor(pr0, m2); pr1 += __shfl_xor(pr1, m2);
        }
        if (row < M) {
#pragma unroll
          for (int nt = 0; nt < 4; nt++)
            outb[(size_t)row * 128 + wn * 64 + nt * 16 + lr] = f2b(acc[mt][nt][r]);
          if (lr == 0) {
            *(float2*)(el + row * 4 + 2 * wn) = make_float2(pl0, pl1);
            *(float2*)(er + row * 4 + 2 * wn) = make_float2(pr0, pr1);
          }
        }
      }
    }
  } else {
#pragma unroll
    for (int mt = 0; mt < 4; mt++) {
      int rbase = wm * 64 + mt * 16 + lk * 4;
#pragma unroll
      for (int r = 0; r < 4; r++) {
        int lrow = rbase + r;
        int row  = row0 + lrow;
        if (row >= M) continue;
#pragma unroll
        for (int nt = 0; nt < 4; nt++) {
          int col = wn * 64 + nt * 16 + lr;
          float v = acc[mt][nt][r];
          if (MODE == 1) {
            outb[(size_t)row * 128 + col] = f2b(v + bias[col]);
          } else {
            float hp = b2f(*(const ushort*)(As + lrow * K2 +
                            ((2 * col) ^ ((lrow & 7) << 4))));
            float cx = b2f(*(const ushort*)(As + lrow * K2 +
                            ((2 * col + 256) ^ ((lrow & 7) << 4))));
            float g = 1.f / (1.f + __expf(-(v + bias[col])));
            outf[(size_t)row * 128 + col] = cx + g * (hp - cx);
          }
        }
      }
    }
  }
}

// ---------------------------------------------------------------------------
// Bucketed aggregation: block = 64 dst nodes, LDS f32 accum [64][128] (32KB).
// Streams the bucket's packed edges; per edge: gather feat[src] (256B
// coalesced per wave), a = exp(lrelu(el[src]+er[dst])), LDS atomic fadd.
// Epilogue: /denom + bias + elu -> bf16. 34KB LDS -> 4 blocks/CU.
// ---------------------------------------------------------------------------
__global__ __launch_bounds__(256) void agg_bucket(
    const uint* __restrict__ packed, const int* __restrict__ boff,
    const ushort* __restrict__ featb, const float* __restrict__ el,
    const float* __restrict__ er, const float* __restrict__ bias,
    ushort* __restrict__ hgatb)
{
  __shared__ float acc_s[64 * 128];   // 32KB
  __shared__ float den_s[64 * 4];
  __shared__ float ers[64 * 4];
  const int b = blockIdx.x, tid = threadIdx.x;
  const int node0 = b * 64;
  for (int i = tid; i < 64 * 128 / 4; i += 256)
    ((float4*)acc_s)[i] = make_float4(0.f, 0.f, 0.f, 0.f);
  {
    int node = node0 + (tid >> 2);
    den_s[tid] = 0.f;
    ers[tid] = (node < NN) ? er[node * 4 + (tid & 3)] : 0.f;
  }
  __syncthreads();

  const int e0 = boff[b], e1 = boff[b + 1];
  const int ln = tid & 63, wv = tid >> 6;
  const int head = ln >> 4;
  const uint* fp = (const uint*)featb;

  for (int e = e0 + wv * 4; e < e1; e += 16) {
    bool vld[4]; uint pw[4]; int s[4], dl[4]; uint fv[4]; float a[4];
#pragma unroll
    for (int j = 0; j < 4; j++) {
      vld[j] = (e + j) < e1;
      pw[j] = vld[j] ? packed[e + j] : 0u;
    }
#pragma unroll
    for (int j = 0; j < 4; j++) { s[j] = pw[j] >> 6; dl[j] = pw[j] & 63; }
#pragma unroll
    for (int j = 0; j < 4; j++)
      fv[j] = vld[j] ? fp[(size_t)s[j] * 64 + ln] : 0u;
#pragma unroll
    for (int j = 0; j < 4; j++) {
      float ev = (vld[j] ? el[s[j] * 4 + head] : 0.f) + ers[dl[j] * 4 + head];
      ev = ev > 0.f ? ev : 0.2f * ev;
      a[j] = __expf(ev);
    }
#pragma unroll
    for (int j = 0; j < 4; j++) {
      if (!vld[j]) continue;
      atomicAdd(&acc_s[dl[j] * 128 + 2 * ln],     a[j] * b2f((ushort)(fv[j] & 0xffff)));
      atomicAdd(&acc_s[dl[j] * 128 + 2 * ln + 1], a[j] * b2f((ushort)(fv[j] >> 16)));
      if ((ln & 15) == 0) atomicAdd(&den_s[dl[j] * 4 + head], a[j]);
    }
  }
  __syncthreads();

  for (int i = tid; i < 64 * 64; i += 256) {
    int r = i >> 6, c = i & 63;          // c: uint index (2 feats)
    int node = node0 + r;
    if (node >= NN) continue;
    float dn = den_s[r * 4 + (c >> 4)];
    float inv = dn > 0.f ? 1.f / dn : 0.f;
    float2 bv = ((const float2*)bias)[c];
    float rx = fmaf(acc_s[r * 128 + 2 * c],     inv, bv.x);
    float ry = fmaf(acc_s[r * 128 + 2 * c + 1], inv, bv.y);
    rx = rx > 0.f ? rx : expm1f(rx);
    ry = ry > 0.f ? ry : expm1f(ry);
    ((uint*)hgatb)[(size_t)node * 64 + c] = (uint)f2b(rx) | ((uint)f2b(ry) << 16);
  }
}

// ---------------------------------------------------------------------------
extern "C" void kernel_launch(void* const* d_in, const int* in_sizes, int n_in,
                              void* d_out, int out_size, void* d_ws, size_t ws_size,
                              hipStream_t stream) {
  const float* h        = (const float*)d_in[0];
  const int*   src      = (const int*)d_in[1];
  const int*   dst      = (const int*)d_in[2];
  const float* ctx      = (const float*)d_in[3];
  const float* W_fc     = (const float*)d_in[4];
  const float* attn_l   = (const float*)d_in[5];
  const float* attn_r   = (const float*)d_in[6];
  const float* bias_gat = (const float*)d_in[7];
  const float* W_proj   = (const float*)d_in[8];
  const float* b_proj   = (const float*)d_in[9];
  const float* W_gate   = (const float*)d_in[10];
  const float* b_gate   = (const float*)d_in[11];
  float* out = (float*)d_out;

  char* ws = (char*)d_ws;
  size_t off = 0;
  auto take = [&](size_t bytes) -> void* {
    void* p = ws + off;
    off += (bytes + 255) & ~(size_t)255;
    return p;
  };
  ushort* featb  = (ushort*)take((size_t)NN * 128 * 2);
  ushort* hgatb  = (ushort*)take((size_t)NN * 128 * 2);
  float*  el     = (float*)take((size_t)NN * 4 * 4);
  float*  er     = (float*)take((size_t)NN * 4 * 4);
  int*    gcnt   = (int*)take((size_t)NBK * 4);
  int*    boff   = (int*)take((size_t)(NBK + 1) * 4);
  int*    gcur   = (int*)take((size_t)NBK * 4);
  uint*   packed = (uint*)take((size_t)NE * 4);
  ushort* Tfc    = (ushort*)take(16384 * 2);
  ushort* Tpr    = (ushort*)take(16384 * 2);
  ushort* Tgt    = (ushort*)take(32768 * 2);
  ushort* hpb = featb;   // featb dead after agg_bucket

  hipMemsetAsync(gcnt, 0, (size_t)NBK * 4, stream);

  const int gb = (NN + 127) / 128;       // 391
  const size_t smem4 = 2 * 128 * 256;    // 64 KB  (KS=4)
  const size_t smem8 = 2 * 128 * 512;    // 128 KB (KS=8)

  cvt_w<<<256, 256, 0, stream>>>(W_fc, W_proj, W_gate, Tfc, Tpr, Tgt);
  // bucket partition
  bhist<<<128, 512, 0, stream>>>(dst, gcnt);
  bscan<<<1, 256, 0, stream>>>(gcnt, boff, gcur);
  bscatter<<<128, 512, 0, stream>>>(src, dst, gcur, packed);
  // feat = h @ W_fc (f32 in, bf16 out) + fused el/er
  mgemm<4, 0><<<gb, 256, smem4, stream>>>(nullptr, h, nullptr, Tfc, nullptr,
                                          attn_l, attn_r, el, er, featb,
                                          nullptr, NN);
  // edge-softmax aggregation -> h_gat (bf16)
  agg_bucket<<<NBK, 256, 0, stream>>>(packed, boff, featb, el, er,
                                      bias_gat, hgatb);
  // h_proj = h_gat @ W_proj + b_proj (bf16 out)
  mgemm<4, 1><<<gb, 256, smem4, stream>>>(hgatb, nullptr, nullptr, Tpr, b_proj,
                                          nullptr, nullptr, nullptr, nullptr,
                                          hpb, nullptr, NN);
  // fused gate GEMM (K=256): g = sigmoid([hp,ctx]@W_gate + b_gate);
  // out = g*hp + (1-g)*ctx
  mgemm<8, 2><<<gb, 256, smem8, stream>>>(hpb, nullptr, ctx, Tgt, b_gate,
                                          nullptr, nullptr, nullptr, nullptr,
                                          nullptr, out, NN);
}

// Round 5
// 264.895 us; speedup vs baseline: 3.4468x; 3.4468x over previous
//
#include <hip/hip_runtime.h>
#include <math.h>

#define NN 50000
#define NE 800000
#define NBK 782   // ceil(NN/64) 64-node dst buckets

typedef __bf16 bf16x8 __attribute__((ext_vector_type(8)));
typedef float  f32x4  __attribute__((ext_vector_type(4)));

__device__ __forceinline__ ushort f2b(float f) {
  union { float f; uint u; } v; v.f = f;
  uint u = v.u;
  return (ushort)((u + 0x7fffu + ((u >> 16) & 1u)) >> 16);  // RNE
}
__device__ __forceinline__ float b2f(ushort b) {
  union { uint u; float f; } v; v.u = ((uint)b) << 16;
  return v.f;
}
__device__ __forceinline__ uint4 cvt8(const float* p) {
  float4 a = *(const float4*)p, b = *(const float4*)(p + 4);
  uint4 u;
  u.x = (uint)f2b(a.x) | ((uint)f2b(a.y) << 16);
  u.y = (uint)f2b(a.z) | ((uint)f2b(a.w) << 16);
  u.z = (uint)f2b(b.x) | ((uint)f2b(b.y) << 16);
  u.w = (uint)f2b(b.z) | ((uint)f2b(b.w) << 16);
  return u;
}

// ---------------------------------------------------------------------------
// cvt_w: weights -> bf16, transposed to [n][k]
// ---------------------------------------------------------------------------
__global__ __launch_bounds__(256) void cvt_w(const float* __restrict__ Wfc,
    const float* __restrict__ Wpr, const float* __restrict__ Wgt,
    ushort* __restrict__ Tfc, ushort* __restrict__ Tpr, ushort* __restrict__ Tgt) {
  int t = blockIdx.x * 256 + threadIdx.x;
  if (t < 16384) {
    int n = t >> 7, k = t & 127;
    Tfc[n * 128 + k] = f2b(Wfc[k * 128 + n]);
  } else if (t < 32768) {
    int i = t - 16384; int n = i >> 7, k = i & 127;
    Tpr[n * 128 + k] = f2b(Wpr[k * 128 + n]);
  } else if (t < 65536) {
    int i = t - 32768; int n = i >> 8, k = i & 255;
    Tgt[n * 256 + k] = f2b(Wgt[k * 128 + n]);
  }
}

// ---------------------------------------------------------------------------
// bucket histogram: LDS-binned per block, one global atomic per bucket.
// ---------------------------------------------------------------------------
__global__ __launch_bounds__(512) void bhist(const int* __restrict__ dst,
                                             int* __restrict__ gcnt) {
  __shared__ int lcnt[NBK];
  const int tid = threadIdx.x;
  for (int i = tid; i < NBK; i += 512) lcnt[i] = 0;
  __syncthreads();
  for (int e = blockIdx.x * 512 + tid; e < NE; e += 128 * 512)
    atomicAdd(&lcnt[dst[e] >> 6], 1);
  __syncthreads();
  for (int i = tid; i < NBK; i += 512) {
    int c = lcnt[i];
    if (c) atomicAdd(&gcnt[i], c);
  }
}

// single-block exclusive scan over NBK bucket counts -> boff + gcursor
__global__ __launch_bounds__(256) void bscan(const int* __restrict__ gcnt,
                                             int* __restrict__ boff,
                                             int* __restrict__ gcursor) {
  __shared__ int ws[4];
  __shared__ int carry;
  const int tid = threadIdx.x, ln = tid & 63, wv = tid >> 6;
  if (tid == 0) carry = 0;
  __syncthreads();
  for (int base = 0; base < NBK; base += 256) {
    int i = base + tid;
    int x = (i < NBK) ? gcnt[i] : 0;
    int v = x;
#pragma unroll
    for (int d = 1; d < 64; d <<= 1) {
      int t = __shfl_up(v, d);
      if (ln >= d) v += t;
    }
    if (ln == 63) ws[wv] = v;
    __syncthreads();
    int w0 = ws[0], w1 = ws[1], w2 = ws[2], w3 = ws[3];
    int woff = (wv == 0) ? 0 : (wv == 1) ? w0 : (wv == 2) ? w0 + w1 : w0 + w1 + w2;
    int excl = carry + woff + v - x;
    if (i < NBK) { boff[i] = excl; gcursor[i] = excl; }
    int tot = w0 + w1 + w2 + w3;
    __syncthreads();
    if (tid == 0) carry += tot;
    __syncthreads();
  }
  if (threadIdx.x == 0) boff[NBK] = NE;
}

// ---------------------------------------------------------------------------
// bucket scatter: block-local LDS counts -> per-bucket range reserve ->
// packed (src<<6 | dstLow) appended. Low write amplification.
// ---------------------------------------------------------------------------
__global__ __launch_bounds__(512) void bscatter(const int* __restrict__ src,
    const int* __restrict__ dst, int* __restrict__ gcursor,
    uint* __restrict__ packed) {
  __shared__ int lcnt[NBK];
  __shared__ int lbase[NBK];
  __shared__ int lrank[NBK];
  const int tid = threadIdx.x;
  const int PER = (NE + 127) / 128;   // 6250
  const int e0 = blockIdx.x * PER;
  const int e1 = min(NE, e0 + PER);
  for (int i = tid; i < NBK; i += 512) { lcnt[i] = 0; lrank[i] = 0; }
  __syncthreads();
  for (int e = e0 + tid; e < e1; e += 512) atomicAdd(&lcnt[dst[e] >> 6], 1);
  __syncthreads();
  for (int i = tid; i < NBK; i += 512) {
    int c = lcnt[i];
    lbase[i] = c ? atomicAdd(&gcursor[i], c) : 0;
  }
  __syncthreads();
  for (int e = e0 + tid; e < e1; e += 512) {
    int d = dst[e], b = d >> 6;
    int r = atomicAdd(&lrank[b], 1);
    packed[lbase[b] + r] = ((uint)src[e] << 6) | (uint)(d & 63);
  }
}

// ---------------------------------------------------------------------------
// per-bucket counting sort: packed (bucket-grouped) -> node-sorted ssrc +
// exact per-node CSR (row_off, deg). One block per bucket, LDS = 3x64 ints.
// ---------------------------------------------------------------------------
__global__ __launch_bounds__(256) void bsort(const uint* __restrict__ packed,
    const int* __restrict__ boff, int* __restrict__ ssrc,
    int* __restrict__ row_off, int* __restrict__ deg) {
  __shared__ int cnt[64], base[64], rank[64];
  const int b = blockIdx.x, tid = threadIdx.x;
  const int e0 = boff[b], e1 = boff[b + 1];
  if (tid < 64) { cnt[tid] = 0; rank[tid] = 0; }
  __syncthreads();
  for (int e = e0 + tid; e < e1; e += 256)
    atomicAdd(&cnt[packed[e] & 63], 1);
  __syncthreads();
  if (tid < 64) {                      // wave 0: scan 64 counts
    int x = cnt[tid];
    int v = x;
#pragma unroll
    for (int d = 1; d < 64; d <<= 1) {
      int t = __shfl_up(v, d);
      if (tid >= d) v += t;
    }
    base[tid] = v - x;
    int node = b * 64 + tid;
    if (node < NN) { row_off[node] = e0 + v - x; deg[node] = x; }
  }
  __syncthreads();
  for (int e = e0 + tid; e < e1; e += 256) {
    uint p = packed[e];
    int dl = p & 63;
    int r = atomicAdd(&rank[dl], 1);
    ssrc[e0 + base[dl] + r] = (int)(p >> 6);
  }
}

// ---------------------------------------------------------------------------
// MFMA GEMM: out[M x 128] = A[M x K] @ Wt^T, K = KS*32.
// MODE 0: A = f32 h (staged-convert); out feat bf16 + fused el/er epilogue.
// MODE 1: A = bf16; out = A@W + bias (bf16).
// MODE 2: A0 = bf16 hp (K 0..127), A1 = f32 ctx (K 128..255, staged-convert);
//         g = sigmoid(acc + bias); out_f32 = g*hp + (1-g)*ctx (hp/ctx from LDS).
// ---------------------------------------------------------------------------
template<int KS, int MODE>
__global__ __launch_bounds__(256) void mgemm(
    const ushort* __restrict__ A0b, const float* __restrict__ A0f,
    const float* __restrict__ A1f, const ushort* __restrict__ Wt,
    const float* __restrict__ bias, const float* __restrict__ al,
    const float* __restrict__ ar, float* __restrict__ el,
    float* __restrict__ er, ushort* __restrict__ outb,
    float* __restrict__ outf, int M)
{
  constexpr int K  = KS * 32;
  constexpr int K2 = K * 2;              // bytes per LDS row
  constexpr int CPR = K2 / 16;           // 16B chunks per row
  constexpr int CHT = 128 * CPR / 256;   // chunks per thread per tile
  extern __shared__ char lds[];
  char* As = lds;
  char* Bs = lds + 128 * K2;
  const int tid  = threadIdx.x;
  const int row0 = blockIdx.x * 128;

#pragma unroll
  for (int c = 0; c < CHT; c++) {
    int idx = tid + c * 256;
    int r  = idx / CPR;
    int kc = idx % CPR;
    int sw = ((kc * 16) ^ ((r & 7) << 4));
    int grow = row0 + r;
    uint4 va = make_uint4(0u, 0u, 0u, 0u);
    if (grow < M) {
      if (MODE == 0) {
        va = cvt8(A0f + (size_t)grow * 128 + kc * 8);
      } else if (MODE == 1) {
        va = *(const uint4*)(A0b + (size_t)grow * 128 + kc * 8);
      } else {
        if (kc < CPR / 2) va = *(const uint4*)(A0b + (size_t)grow * 128 + kc * 8);
        else va = cvt8(A1f + (size_t)grow * 128 + (kc - CPR / 2) * 8);
      }
    }
    *(uint4*)(As + r * K2 + sw) = va;
    uint4 vb = *(const uint4*)(Wt + (size_t)idx * 8);
    *(uint4*)(Bs + r * K2 + sw) = vb;
  }
  __syncthreads();

  const int ln = tid & 63, wv = tid >> 6;
  const int wm = wv >> 1, wn = wv & 1;
  const int lr = ln & 15, lk = ln >> 4;

  f32x4 acc[4][4] = {};
#pragma unroll
  for (int ks = 0; ks < KS; ks++) {
    int k2 = ks * 64 + lk * 16;
    bf16x8 af[4], bfr[4];
#pragma unroll
    for (int t = 0; t < 4; t++) {
      int arr = wm * 64 + t * 16 + lr;
      af[t]  = *(const bf16x8*)(As + arr * K2 + (k2 ^ ((arr & 7) << 4)));
      int bn = wn * 64 + t * 16 + lr;
      bfr[t] = *(const bf16x8*)(Bs + bn * K2 + (k2 ^ ((bn & 7) << 4)));
    }
#pragma unroll
    for (int mt = 0; mt < 4; mt++)
#pragma unroll
      for (int nt = 0; nt < 4; nt++)
        acc[mt][nt] = __builtin_amdgcn_mfma_f32_16x16x32_bf16(
            af[mt], bfr[nt], acc[mt][nt], 0, 0, 0);
  }

  if (MODE == 0) {
    float alv[4], arv[4];
#pragma unroll
    for (int nt = 0; nt < 4; nt++) {
      int col = wn * 64 + nt * 16 + lr;
      alv[nt] = al[col]; arv[nt] = ar[col];
    }
#pragma unroll
    for (int mt = 0; mt < 4; mt++) {
#pragma unroll
      for (int r = 0; r < 4; r++) {
        int row = row0 + wm * 64 + mt * 16 + lk * 4 + r;
        float pl0 = acc[mt][0][r] * alv[0] + acc[mt][1][r] * alv[1];
        float pl1 = acc[mt][2][r] * alv[2] + acc[mt][3][r] * alv[3];
        float pr0 = acc[mt][0][r] * arv[0] + acc[mt][1][r] * arv[1];
        float pr1 = acc[mt][2][r] * arv[2] + acc[mt][3][r] * arv[3];
#pragma unroll
        for (int m2 = 1; m2 < 16; m2 <<= 1) {
          pl0 += __shfl_xor(pl0, m2); pl1 += __shfl_xor(pl1, m2);
          pr0 += __shfl_xor(pr0, m2); pr1 += __shfl_xor(pr1, m2);
        }
        if (row < M) {
#pragma unroll
          for (int nt = 0; nt < 4; nt++)
            outb[(size_t)row * 128 + wn * 64 + nt * 16 + lr] = f2b(acc[mt][nt][r]);
          if (lr == 0) {
            *(float2*)(el + row * 4 + 2 * wn) = make_float2(pl0, pl1);
            *(float2*)(er + row * 4 + 2 * wn) = make_float2(pr0, pr1);
          }
        }
      }
    }
  } else {
#pragma unroll
    for (int mt = 0; mt < 4; mt++) {
      int rbase = wm * 64 + mt * 16 + lk * 4;
#pragma unroll
      for (int r = 0; r < 4; r++) {
        int lrow = rbase + r;
        int row  = row0 + lrow;
        if (row >= M) continue;
#pragma unroll
        for (int nt = 0; nt < 4; nt++) {
          int col = wn * 64 + nt * 16 + lr;
          float v = acc[mt][nt][r];
          if (MODE == 1) {
            outb[(size_t)row * 128 + col] = f2b(v + bias[col]);
          } else {
            float hp = b2f(*(const ushort*)(As + lrow * K2 +
                            ((2 * col) ^ ((lrow & 7) << 4))));
            float cx = b2f(*(const ushort*)(As + lrow * K2 +
                            ((2 * col + 256) ^ ((lrow & 7) << 4))));
            float g = 1.f / (1.f + __expf(-(v + bias[col])));
            outf[(size_t)row * 128 + col] = cx + g * (hp - cx);
          }
        }
      }
    }
  }
}

// ---------------------------------------------------------------------------
// Aggregation (R2-proven structure): one wave per dst node; lane covers
// features (2l,2l+1) bf16; register accumulation; 2-way edge unroll.
// rst = (sum a*feat[src]) / (sum a); +bias; elu -> h_gat (bf16).
// ---------------------------------------------------------------------------
__global__ __launch_bounds__(256) void agg_k(
    const ushort* __restrict__ featb, const float* __restrict__ el,
    const float* __restrict__ er, const int* __restrict__ deg,
    const int* __restrict__ row_off, const int* __restrict__ ssrc,
    const float* __restrict__ bias, ushort* __restrict__ hgatb)
{
  const int wid = (blockIdx.x * 256 + threadIdx.x) >> 6;
  if (wid >= NN) return;
  const int ln = threadIdx.x & 63;
  const int head = ln >> 4;
  const int cnt = deg[wid];
  const int start = row_off[wid];
  const float erh = er[wid * 4 + head];
  const uint* f2 = (const uint*)featb;

  float ax0 = 0.f, ay0 = 0.f, dn0 = 0.f;
  float ax1 = 0.f, ay1 = 0.f, dn1 = 0.f;
  for (int base = 0; base < cnt; base += 64) {
    int m = min(64, cnt - base);
    int sv = (ln < m) ? ssrc[start + base + ln] : 0;
    int i = 0;
    for (; i + 1 < m; i += 2) {
      int s0 = __shfl(sv, i), s1 = __shfl(sv, i + 1);
      float e0 = el[s0 * 4 + head] + erh;
      float e1 = el[s1 * 4 + head] + erh;
      uint u0 = f2[(size_t)s0 * 64 + ln];
      uint u1 = f2[(size_t)s1 * 64 + ln];
      e0 = e0 > 0.f ? e0 : 0.2f * e0;
      e1 = e1 > 0.f ? e1 : 0.2f * e1;
      float a0 = __expf(e0), a1 = __expf(e1);
      ax0 = fmaf(a0, b2f((ushort)(u0 & 0xffff)), ax0);
      ay0 = fmaf(a0, b2f((ushort)(u0 >> 16)), ay0);
      dn0 += a0;
      ax1 = fmaf(a1, b2f((ushort)(u1 & 0xffff)), ax1);
      ay1 = fmaf(a1, b2f((ushort)(u1 >> 16)), ay1);
      dn1 += a1;
    }
    if (i < m) {
      int s0 = __shfl(sv, i);
      float e0 = el[s0 * 4 + head] + erh;
      uint u0 = f2[(size_t)s0 * 64 + ln];
      e0 = e0 > 0.f ? e0 : 0.2f * e0;
      float a0 = __expf(e0);
      ax0 = fmaf(a0, b2f((ushort)(u0 & 0xffff)), ax0);
      ay0 = fmaf(a0, b2f((ushort)(u0 >> 16)), ay0);
      dn0 += a0;
    }
  }
  float dn = dn0 + dn1;
  float inv = (cnt > 0) ? (1.0f / dn) : 0.0f;
  float2 bv = ((const float2*)bias)[ln];
  float rx = fmaf(ax0 + ax1, inv, bv.x);
  float ry = fmaf(ay0 + ay1, inv, bv.y);
  rx = rx > 0.f ? rx : expm1f(rx);
  ry = ry > 0.f ? ry : expm1f(ry);
  uint o = (uint)f2b(rx) | ((uint)f2b(ry) << 16);
  ((uint*)hgatb)[(size_t)wid * 64 + ln] = o;
}

// ---------------------------------------------------------------------------
extern "C" void kernel_launch(void* const* d_in, const int* in_sizes, int n_in,
                              void* d_out, int out_size, void* d_ws, size_t ws_size,
                              hipStream_t stream) {
  const float* h        = (const float*)d_in[0];
  const int*   src      = (const int*)d_in[1];
  const int*   dst      = (const int*)d_in[2];
  const float* ctx      = (const float*)d_in[3];
  const float* W_fc     = (const float*)d_in[4];
  const float* attn_l   = (const float*)d_in[5];
  const float* attn_r   = (const float*)d_in[6];
  const float* bias_gat = (const float*)d_in[7];
  const float* W_proj   = (const float*)d_in[8];
  const float* b_proj   = (const float*)d_in[9];
  const float* W_gate   = (const float*)d_in[10];
  const float* b_gate   = (const float*)d_in[11];
  float* out = (float*)d_out;

  char* ws = (char*)d_ws;
  size_t off = 0;
  auto take = [&](size_t bytes) -> void* {
    void* p = ws + off;
    off += (bytes + 255) & ~(size_t)255;
    return p;
  };
  ushort* featb  = (ushort*)take((size_t)NN * 128 * 2);
  ushort* hgatb  = (ushort*)take((size_t)NN * 128 * 2);
  float*  el     = (float*)take((size_t)NN * 4 * 4);
  float*  er     = (float*)take((size_t)NN * 4 * 4);
  int*    gcnt   = (int*)take((size_t)NBK * 4);
  int*    boff   = (int*)take((size_t)(NBK + 1) * 4);
  int*    gcur   = (int*)take((size_t)NBK * 4);
  uint*   packed = (uint*)take((size_t)NE * 4);
  int*    ssrc   = (int*)take((size_t)NE * 4);
  int*    row_off= (int*)take((size_t)NN * 4);
  int*    deg    = (int*)take((size_t)NN * 4);
  ushort* Tfc    = (ushort*)take(16384 * 2);
  ushort* Tpr    = (ushort*)take(16384 * 2);
  ushort* Tgt    = (ushort*)take(32768 * 2);
  ushort* hpb = featb;   // featb dead after agg_k

  hipMemsetAsync(gcnt, 0, (size_t)NBK * 4, stream);

  const int gb = (NN + 127) / 128;       // 391
  const size_t smem4 = 2 * 128 * 256;    // 64 KB  (KS=4)
  const size_t smem8 = 2 * 128 * 512;    // 128 KB (KS=8)

  cvt_w<<<256, 256, 0, stream>>>(W_fc, W_proj, W_gate, Tfc, Tpr, Tgt);
  // bucket partition + per-bucket counting sort -> node-sorted CSR
  bhist<<<128, 512, 0, stream>>>(dst, gcnt);
  bscan<<<1, 256, 0, stream>>>(gcnt, boff, gcur);
  bscatter<<<128, 512, 0, stream>>>(src, dst, gcur, packed);
  bsort<<<NBK, 256, 0, stream>>>(packed, boff, ssrc, row_off, deg);
  // feat = h @ W_fc (f32 in, bf16 out) + fused el/er
  mgemm<4, 0><<<gb, 256, smem4, stream>>>(nullptr, h, nullptr, Tfc, nullptr,
                                          attn_l, attn_r, el, er, featb,
                                          nullptr, NN);
  // edge-softmax aggregation -> h_gat (bf16), register accumulation
  agg_k<<<12500, 256, 0, stream>>>(featb, el, er, deg, row_off, ssrc,
                                   bias_gat, hgatb);
  // h_proj = h_gat @ W_proj + b_proj (bf16 out)
  mgemm<4, 1><<<gb, 256, smem4, stream>>>(hgatb, nullptr, nullptr, Tpr, b_proj,
                                          nullptr, nullptr, nullptr, nullptr,
                                          hpb, nullptr, NN);
  // fused gate GEMM (K=256): g = sigmoid([hp,ctx]@W_gate + b_gate);
  // out = g*hp + (1-g)*ctx
  mgemm<8, 2><<<gb, 256, smem8, stream>>>(hpb, nullptr, ctx, Tgt, b_gate,
                                          nullptr, nullptr, nullptr, nullptr,
                                          nullptr, out, NN);
}

// Round 6
// 256.197 us; speedup vs baseline: 3.5638x; 1.0339x over previous
//
#include <hip/hip_runtime.h>
#include <math.h>

#define NN 50000
#define NE 800000
#define NBK 782   // ceil(NN/64) 64-node dst buckets

typedef __bf16 bf16x8 __attribute__((ext_vector_type(8)));
typedef float  f32x4  __attribute__((ext_vector_type(4)));

__device__ __forceinline__ ushort f2b(float f) {
  union { float f; uint u; } v; v.f = f;
  uint u = v.u;
  return (ushort)((u + 0x7fffu + ((u >> 16) & 1u)) >> 16);  // RNE
}
__device__ __forceinline__ float b2f(ushort b) {
  union { uint u; float f; } v; v.u = ((uint)b) << 16;
  return v.f;
}
__device__ __forceinline__ uint4 cvt8(const float* p) {
  float4 a = *(const float4*)p, b = *(const float4*)(p + 4);
  uint4 u;
  u.x = (uint)f2b(a.x) | ((uint)f2b(a.y) << 16);
  u.y = (uint)f2b(a.z) | ((uint)f2b(a.w) << 16);
  u.z = (uint)f2b(b.x) | ((uint)f2b(b.y) << 16);
  u.w = (uint)f2b(b.z) | ((uint)f2b(b.w) << 16);
  return u;
}

// ---------------------------------------------------------------------------
// cvt_w: weights -> bf16, transposed to [n][k]
// ---------------------------------------------------------------------------
__global__ __launch_bounds__(256) void cvt_w(const float* __restrict__ Wfc,
    const float* __restrict__ Wpr, const float* __restrict__ Wgt,
    ushort* __restrict__ Tfc, ushort* __restrict__ Tpr, ushort* __restrict__ Tgt) {
  int t = blockIdx.x * 256 + threadIdx.x;
  if (t < 16384) {
    int n = t >> 7, k = t & 127;
    Tfc[n * 128 + k] = f2b(Wfc[k * 128 + n]);
  } else if (t < 32768) {
    int i = t - 16384; int n = i >> 7, k = i & 127;
    Tpr[n * 128 + k] = f2b(Wpr[k * 128 + n]);
  } else if (t < 65536) {
    int i = t - 32768; int n = i >> 8, k = i & 255;
    Tgt[n * 256 + k] = f2b(Wgt[k * 128 + n]);
  }
}

// ---------------------------------------------------------------------------
// bucket histogram: LDS-binned per block, one global atomic per bucket.
// ---------------------------------------------------------------------------
__global__ __launch_bounds__(512) void bhist(const int* __restrict__ dst,
                                             int* __restrict__ gcnt) {
  __shared__ int lcnt[NBK];
  const int tid = threadIdx.x;
  for (int i = tid; i < NBK; i += 512) lcnt[i] = 0;
  __syncthreads();
  for (int e = blockIdx.x * 512 + tid; e < NE; e += 256 * 512)
    atomicAdd(&lcnt[dst[e] >> 6], 1);
  __syncthreads();
  for (int i = tid; i < NBK; i += 512) {
    int c = lcnt[i];
    if (c) atomicAdd(&gcnt[i], c);
  }
}

// single-block exclusive scan over NBK bucket counts -> boff + gcursor
__global__ __launch_bounds__(256) void bscan(const int* __restrict__ gcnt,
                                             int* __restrict__ boff,
                                             int* __restrict__ gcursor) {
  __shared__ int ws[4];
  __shared__ int carry;
  const int tid = threadIdx.x, ln = tid & 63, wv = tid >> 6;
  if (tid == 0) carry = 0;
  __syncthreads();
  for (int base = 0; base < NBK; base += 256) {
    int i = base + tid;
    int x = (i < NBK) ? gcnt[i] : 0;
    int v = x;
#pragma unroll
    for (int d = 1; d < 64; d <<= 1) {
      int t = __shfl_up(v, d);
      if (ln >= d) v += t;
    }
    if (ln == 63) ws[wv] = v;
    __syncthreads();
    int w0 = ws[0], w1 = ws[1], w2 = ws[2], w3 = ws[3];
    int woff = (wv == 0) ? 0 : (wv == 1) ? w0 : (wv == 2) ? w0 + w1 : w0 + w1 + w2;
    int excl = carry + woff + v - x;
    if (i < NBK) { boff[i] = excl; gcursor[i] = excl; }
    int tot = w0 + w1 + w2 + w3;
    __syncthreads();
    if (tid == 0) carry += tot;
    __syncthreads();
  }
  if (threadIdx.x == 0) boff[NBK] = NE;
}

// ---------------------------------------------------------------------------
// bucket scatter: block-local LDS counts -> per-bucket range reserve ->
// packed (src<<6 | dstLow) appended. Low write amplification.
// ---------------------------------------------------------------------------
__global__ __launch_bounds__(512) void bscatter(const int* __restrict__ src,
    const int* __restrict__ dst, int* __restrict__ gcursor,
    uint* __restrict__ packed) {
  __shared__ int lcnt[NBK];
  __shared__ int lbase[NBK];
  __shared__ int lrank[NBK];
  const int tid = threadIdx.x;
  const int PER = (NE + 255) / 256;   // 3125
  const int e0 = blockIdx.x * PER;
  const int e1 = min(NE, e0 + PER);
  for (int i = tid; i < NBK; i += 512) { lcnt[i] = 0; lrank[i] = 0; }
  __syncthreads();
  for (int e = e0 + tid; e < e1; e += 512) atomicAdd(&lcnt[dst[e] >> 6], 1);
  __syncthreads();
  for (int i = tid; i < NBK; i += 512) {
    int c = lcnt[i];
    lbase[i] = c ? atomicAdd(&gcursor[i], c) : 0;
  }
  __syncthreads();
  for (int e = e0 + tid; e < e1; e += 512) {
    int d = dst[e], b = d >> 6;
    int r = atomicAdd(&lrank[b], 1);
    packed[lbase[b] + r] = ((uint)src[e] << 6) | (uint)(d & 63);
  }
}

// ---------------------------------------------------------------------------
// per-bucket counting sort: packed (bucket-grouped) -> node-sorted ssrc +
// exact per-node CSR (row_off, deg). One block per bucket.
// ---------------------------------------------------------------------------
__global__ __launch_bounds__(256) void bsort(const uint* __restrict__ packed,
    const int* __restrict__ boff, int* __restrict__ ssrc,
    int* __restrict__ row_off, int* __restrict__ deg) {
  __shared__ int cnt[64], base[64], rank[64];
  const int b = blockIdx.x, tid = threadIdx.x;
  const int e0 = boff[b], e1 = boff[b + 1];
  if (tid < 64) { cnt[tid] = 0; rank[tid] = 0; }
  __syncthreads();
  for (int e = e0 + tid; e < e1; e += 256)
    atomicAdd(&cnt[packed[e] & 63], 1);
  __syncthreads();
  if (tid < 64) {                      // wave 0: scan 64 counts
    int x = cnt[tid];
    int v = x;
#pragma unroll
    for (int d = 1; d < 64; d <<= 1) {
      int t = __shfl_up(v, d);
      if (tid >= d) v += t;
    }
    base[tid] = v - x;
    int node = b * 64 + tid;
    if (node < NN) { row_off[node] = e0 + v - x; deg[node] = x; }
  }
  __syncthreads();
  for (int e = e0 + tid; e < e1; e += 256) {
    uint p = packed[e];
    int dl = p & 63;
    int r = atomicAdd(&rank[dl], 1);
    ssrc[e0 + base[dl] + r] = (int)(p >> 6);
  }
}

// ---------------------------------------------------------------------------
// MFMA GEMM: out[M x 128] = A[M x K] @ Wt^T, K = KS*32.
// 64-row tiles, 256 thr = 4 waves (2x2), wave = 32x64 (acc[2][4]).
// A-tile only in LDS (XOR-swizzled); B fragments loaded DIRECT FROM GLOBAL
// (Wt [n][k] bf16; one bf-load = 16 fully-consumed 64B lines/wave, L1/L2-hot).
// MODE 0: A=f32 h (staged cvt); out feat bf16 + fused el/er.
// MODE 1: A=bf16; out = A@W + bias (bf16).
// MODE 2: A0=bf16 hp (k<128), A1=f32 ctx (k>=128, staged cvt);
//         g=sigmoid(acc+bias); out_f32 = g*hp+(1-g)*ctx (hp/ctx from LDS).
// ---------------------------------------------------------------------------
template<int KS, int MODE>
__global__ __launch_bounds__(256) void mgemm(
    const ushort* __restrict__ A0b, const float* __restrict__ A0f,
    const float* __restrict__ A1f, const ushort* __restrict__ Wt,
    const float* __restrict__ bias, const float* __restrict__ al,
    const float* __restrict__ ar, float* __restrict__ el,
    float* __restrict__ er, ushort* __restrict__ outb,
    float* __restrict__ outf, int M)
{
  constexpr int K  = KS * 32;
  constexpr int K2 = K * 2;              // bytes per LDS row
  constexpr int CPR = K2 / 16;           // 16B chunks per row (16 or 32)
  constexpr int CHT = 64 * CPR / 256;    // chunks per thread (4 or 8)
  extern __shared__ char lds[];
  char* As = lds;
  const int tid  = threadIdx.x;
  const int row0 = blockIdx.x * 64;

#pragma unroll
  for (int c = 0; c < CHT; c++) {
    int idx = tid + c * 256;
    int r  = idx / CPR;
    int kc = idx % CPR;
    int sw = ((kc * 16) ^ ((r & 7) << 4));
    int grow = row0 + r;
    uint4 va = make_uint4(0u, 0u, 0u, 0u);
    if (grow < M) {
      if (MODE == 0) {
        va = cvt8(A0f + (size_t)grow * 128 + kc * 8);
      } else if (MODE == 1) {
        va = *(const uint4*)(A0b + (size_t)grow * 128 + kc * 8);
      } else {
        if (kc < CPR / 2) va = *(const uint4*)(A0b + (size_t)grow * 128 + kc * 8);
        else va = cvt8(A1f + (size_t)grow * 128 + (kc - CPR / 2) * 8);
      }
    }
    *(uint4*)(As + r * K2 + sw) = va;
  }
  __syncthreads();

  const int ln = tid & 63, wv = tid >> 6;
  const int wm = wv >> 1, wn = wv & 1;
  const int lr = ln & 15, lk = ln >> 4;

  f32x4 acc[2][4] = {};
#pragma unroll
  for (int ks = 0; ks < KS; ks++) {
    int k2 = ks * 64 + lk * 16;          // byte offset within a row
    bf16x8 af[2], bfr[4];
#pragma unroll
    for (int mt = 0; mt < 2; mt++) {
      int arr = wm * 32 + mt * 16 + lr;
      af[mt] = *(const bf16x8*)(As + arr * K2 + (k2 ^ ((arr & 7) << 4)));
    }
#pragma unroll
    for (int nt = 0; nt < 4; nt++) {
      int bn = wn * 64 + nt * 16 + lr;
      bfr[nt] = *(const bf16x8*)(Wt + (size_t)bn * K + ks * 32 + lk * 8);
    }
#pragma unroll
    for (int mt = 0; mt < 2; mt++)
#pragma unroll
      for (int nt = 0; nt < 4; nt++)
        acc[mt][nt] = __builtin_amdgcn_mfma_f32_16x16x32_bf16(
            af[mt], bfr[nt], acc[mt][nt], 0, 0, 0);
  }

  if (MODE == 0) {
    float alv[4], arv[4];
#pragma unroll
    for (int nt = 0; nt < 4; nt++) {
      int col = wn * 64 + nt * 16 + lr;
      alv[nt] = al[col]; arv[nt] = ar[col];
    }
#pragma unroll
    for (int mt = 0; mt < 2; mt++) {
#pragma unroll
      for (int r = 0; r < 4; r++) {
        int row = row0 + wm * 32 + mt * 16 + lk * 4 + r;
        float pl0 = acc[mt][0][r] * alv[0] + acc[mt][1][r] * alv[1];
        float pl1 = acc[mt][2][r] * alv[2] + acc[mt][3][r] * alv[3];
        float pr0 = acc[mt][0][r] * arv[0] + acc[mt][1][r] * arv[1];
        float pr1 = acc[mt][2][r] * arv[2] + acc[mt][3][r] * arv[3];
#pragma unroll
        for (int m2 = 1; m2 < 16; m2 <<= 1) {
          pl0 += __shfl_xor(pl0, m2); pl1 += __shfl_xor(pl1, m2);
          pr0 += __shfl_xor(pr0, m2); pr1 += __shfl_xor(pr1, m2);
        }
        if (row < M) {
#pragma unroll
          for (int nt = 0; nt < 4; nt++)
            outb[(size_t)row * 128 + wn * 64 + nt * 16 + lr] = f2b(acc[mt][nt][r]);
          if (lr == 0) {
            *(float2*)(el + row * 4 + 2 * wn) = make_float2(pl0, pl1);
            *(float2*)(er + row * 4 + 2 * wn) = make_float2(pr0, pr1);
          }
        }
      }
    }
  } else {
#pragma unroll
    for (int mt = 0; mt < 2; mt++) {
      int rbase = wm * 32 + mt * 16 + lk * 4;
#pragma unroll
      for (int r = 0; r < 4; r++) {
        int lrow = rbase + r;
        int row  = row0 + lrow;
        if (row >= M) continue;
#pragma unroll
        for (int nt = 0; nt < 4; nt++) {
          int col = wn * 64 + nt * 16 + lr;
          float v = acc[mt][nt][r];
          if (MODE == 1) {
            outb[(size_t)row * 128 + col] = f2b(v + bias[col]);
          } else {
            float hp = b2f(*(const ushort*)(As + lrow * K2 +
                            ((2 * col) ^ ((lrow & 7) << 4))));
            float cx = b2f(*(const ushort*)(As + lrow * K2 +
                            ((2 * col + 256) ^ ((lrow & 7) << 4))));
            float g = 1.f / (1.f + __expf(-(v + bias[col])));
            outf[(size_t)row * 128 + col] = cx + g * (hp - cx);
          }
        }
      }
    }
  }
}

// ---------------------------------------------------------------------------
// Aggregation: one wave per dst node; lane covers features (2l,2l+1) bf16;
// register accumulation; 2-way edge unroll.
// ---------------------------------------------------------------------------
__global__ __launch_bounds__(256) void agg_k(
    const ushort* __restrict__ featb, const float* __restrict__ el,
    const float* __restrict__ er, const int* __restrict__ deg,
    const int* __restrict__ row_off, const int* __restrict__ ssrc,
    const float* __restrict__ bias, ushort* __restrict__ hgatb)
{
  const int wid = (blockIdx.x * 256 + threadIdx.x) >> 6;
  if (wid >= NN) return;
  const int ln = threadIdx.x & 63;
  const int head = ln >> 4;
  const int cnt = deg[wid];
  const int start = row_off[wid];
  const float erh = er[wid * 4 + head];
  const uint* f2 = (const uint*)featb;

  float ax0 = 0.f, ay0 = 0.f, dn0 = 0.f;
  float ax1 = 0.f, ay1 = 0.f, dn1 = 0.f;
  for (int base = 0; base < cnt; base += 64) {
    int m = min(64, cnt - base);
    int sv = (ln < m) ? ssrc[start + base + ln] : 0;
    int i = 0;
    for (; i + 1 < m; i += 2) {
      int s0 = __shfl(sv, i), s1 = __shfl(sv, i + 1);
      float e0 = el[s0 * 4 + head] + erh;
      float e1 = el[s1 * 4 + head] + erh;
      uint u0 = f2[(size_t)s0 * 64 + ln];
      uint u1 = f2[(size_t)s1 * 64 + ln];
      e0 = e0 > 0.f ? e0 : 0.2f * e0;
      e1 = e1 > 0.f ? e1 : 0.2f * e1;
      float a0 = __expf(e0), a1 = __expf(e1);
      ax0 = fmaf(a0, b2f((ushort)(u0 & 0xffff)), ax0);
      ay0 = fmaf(a0, b2f((ushort)(u0 >> 16)), ay0);
      dn0 += a0;
      ax1 = fmaf(a1, b2f((ushort)(u1 & 0xffff)), ax1);
      ay1 = fmaf(a1, b2f((ushort)(u1 >> 16)), ay1);
      dn1 += a1;
    }
    if (i < m) {
      int s0 = __shfl(sv, i);
      float e0 = el[s0 * 4 + head] + erh;
      uint u0 = f2[(size_t)s0 * 64 + ln];
      e0 = e0 > 0.f ? e0 : 0.2f * e0;
      float a0 = __expf(e0);
      ax0 = fmaf(a0, b2f((ushort)(u0 & 0xffff)), ax0);
      ay0 = fmaf(a0, b2f((ushort)(u0 >> 16)), ay0);
      dn0 += a0;
    }
  }
  float dn = dn0 + dn1;
  float inv = (cnt > 0) ? (1.0f / dn) : 0.0f;
  float2 bv = ((const float2*)bias)[ln];
  float rx = fmaf(ax0 + ax1, inv, bv.x);
  float ry = fmaf(ay0 + ay1, inv, bv.y);
  rx = rx > 0.f ? rx : expm1f(rx);
  ry = ry > 0.f ? ry : expm1f(ry);
  uint o = (uint)f2b(rx) | ((uint)f2b(ry) << 16);
  ((uint*)hgatb)[(size_t)wid * 64 + ln] = o;
}

// ---------------------------------------------------------------------------
extern "C" void kernel_launch(void* const* d_in, const int* in_sizes, int n_in,
                              void* d_out, int out_size, void* d_ws, size_t ws_size,
                              hipStream_t stream) {
  const float* h        = (const float*)d_in[0];
  const int*   src      = (const int*)d_in[1];
  const int*   dst      = (const int*)d_in[2];
  const float* ctx      = (const float*)d_in[3];
  const float* W_fc     = (const float*)d_in[4];
  const float* attn_l   = (const float*)d_in[5];
  const float* attn_r   = (const float*)d_in[6];
  const float* bias_gat = (const float*)d_in[7];
  const float* W_proj   = (const float*)d_in[8];
  const float* b_proj   = (const float*)d_in[9];
  const float* W_gate   = (const float*)d_in[10];
  const float* b_gate   = (const float*)d_in[11];
  float* out = (float*)d_out;

  char* ws = (char*)d_ws;
  size_t off = 0;
  auto take = [&](size_t bytes) -> void* {
    void* p = ws + off;
    off += (bytes + 255) & ~(size_t)255;
    return p;
  };
  ushort* featb  = (ushort*)take((size_t)NN * 128 * 2);
  ushort* hgatb  = (ushort*)take((size_t)NN * 128 * 2);
  float*  el     = (float*)take((size_t)NN * 4 * 4);
  float*  er     = (float*)take((size_t)NN * 4 * 4);
  int*    gcnt   = (int*)take((size_t)NBK * 4);
  int*    boff   = (int*)take((size_t)(NBK + 1) * 4);
  int*    gcur   = (int*)take((size_t)NBK * 4);
  uint*   packed = (uint*)take((size_t)NE * 4);
  int*    ssrc   = (int*)take((size_t)NE * 4);
  int*    row_off= (int*)take((size_t)NN * 4);
  int*    deg    = (int*)take((size_t)NN * 4);
  ushort* Tfc    = (ushort*)take(16384 * 2);
  ushort* Tpr    = (ushort*)take(16384 * 2);
  ushort* Tgt    = (ushort*)take(32768 * 2);
  ushort* hpb = featb;   // featb dead after agg_k

  hipMemsetAsync(gcnt, 0, (size_t)NBK * 4, stream);

  const int gb = (NN + 63) / 64;         // 782
  const size_t smem4 = 64 * 256;         // 16 KB (KS=4, A-tile only)
  const size_t smem8 = 64 * 512;         // 32 KB (KS=8, A-tile only)

  cvt_w<<<256, 256, 0, stream>>>(W_fc, W_proj, W_gate, Tfc, Tpr, Tgt);
  // bucket partition + per-bucket counting sort -> node-sorted CSR
  bhist<<<256, 512, 0, stream>>>(dst, gcnt);
  bscan<<<1, 256, 0, stream>>>(gcnt, boff, gcur);
  bscatter<<<256, 512, 0, stream>>>(src, dst, gcur, packed);
  bsort<<<NBK, 256, 0, stream>>>(packed, boff, ssrc, row_off, deg);
  // feat = h @ W_fc (f32 in, bf16 out) + fused el/er
  mgemm<4, 0><<<gb, 256, smem4, stream>>>(nullptr, h, nullptr, Tfc, nullptr,
                                          attn_l, attn_r, el, er, featb,
                                          nullptr, NN);
  // edge-softmax aggregation -> h_gat (bf16), register accumulation
  agg_k<<<12500, 256, 0, stream>>>(featb, el, er, deg, row_off, ssrc,
                                   bias_gat, hgatb);
  // h_proj = h_gat @ W_proj + b_proj (bf16 out)
  mgemm<4, 1><<<gb, 256, smem4, stream>>>(hgatb, nullptr, nullptr, Tpr, b_proj,
                                          nullptr, nullptr, nullptr, nullptr,
                                          hpb, nullptr, NN);
  // fused gate GEMM (K=256): g = sigmoid([hp,ctx]@W_gate + b_gate);
  // out = g*hp + (1-g)*ctx
  mgemm<8, 2><<<gb, 256, smem8, stream>>>(hpb, nullptr, ctx, Tgt, b_gate,
                                          nullptr, nullptr, nullptr, nullptr,
                                          nullptr, out, NN);
}

// Round 8
// 235.333 us; speedup vs baseline: 3.8798x; 1.0887x over previous
//
#include <hip/hip_runtime.h>
#include <math.h>

#define NN 50000
#define NE 800000
#define NBK 782   // ceil(NN/64) 64-node dst buckets

typedef __bf16 bf16x8 __attribute__((ext_vector_type(8)));
typedef float  f32x4  __attribute__((ext_vector_type(4)));

__device__ __forceinline__ ushort f2b(float f) {
  union { float f; uint u; } v; v.f = f;
  uint u = v.u;
  return (ushort)((u + 0x7fffu + ((u >> 16) & 1u)) >> 16);  // RNE
}
__device__ __forceinline__ float b2f(ushort b) {
  union { uint u; float f; } v; v.u = ((uint)b) << 16;
  return v.f;
}
__device__ __forceinline__ uint4 cvt8(const float* p) {
  float4 a = *(const float4*)p, b = *(const float4*)(p + 4);
  uint4 u;
  u.x = (uint)f2b(a.x) | ((uint)f2b(a.y) << 16);
  u.y = (uint)f2b(a.z) | ((uint)f2b(a.w) << 16);
  u.z = (uint)f2b(b.x) | ((uint)f2b(b.y) << 16);
  u.w = (uint)f2b(b.z) | ((uint)f2b(b.w) << 16);
  return u;
}

// ---------------------------------------------------------------------------
// cvt_w: weights -> bf16, transposed to [n][k]
// ---------------------------------------------------------------------------
__global__ __launch_bounds__(256) void cvt_w(const float* __restrict__ Wfc,
    const float* __restrict__ Wpr, const float* __restrict__ Wgt,
    ushort* __restrict__ Tfc, ushort* __restrict__ Tpr, ushort* __restrict__ Tgt) {
  int t = blockIdx.x * 256 + threadIdx.x;
  if (t < 16384) {
    int n = t >> 7, k = t & 127;
    Tfc[n * 128 + k] = f2b(Wfc[k * 128 + n]);
  } else if (t < 32768) {
    int i = t - 16384; int n = i >> 7, k = i & 127;
    Tpr[n * 128 + k] = f2b(Wpr[k * 128 + n]);
  } else if (t < 65536) {
    int i = t - 32768; int n = i >> 8, k = i & 255;
    Tgt[n * 256 + k] = f2b(Wgt[k * 128 + n]);
  }
}

// ---------------------------------------------------------------------------
// bucket histogram: LDS-binned per block, one global atomic per bucket.
// ---------------------------------------------------------------------------
__global__ __launch_bounds__(512) void bhist(const int* __restrict__ dst,
                                             int* __restrict__ gcnt) {
  __shared__ int lcnt[NBK];
  const int tid = threadIdx.x;
  for (int i = tid; i < NBK; i += 512) lcnt[i] = 0;
  __syncthreads();
  for (int e = blockIdx.x * 512 + tid; e < NE; e += 256 * 512)
    atomicAdd(&lcnt[dst[e] >> 6], 1);
  __syncthreads();
  for (int i = tid; i < NBK; i += 512) {
    int c = lcnt[i];
    if (c) atomicAdd(&gcnt[i], c);
  }
}

// single-block exclusive scan over NBK bucket counts -> boff + gcursor
__global__ __launch_bounds__(256) void bscan(const int* __restrict__ gcnt,
                                             int* __restrict__ boff,
                                             int* __restrict__ gcursor) {
  __shared__ int ws[4];
  __shared__ int carry;
  const int tid = threadIdx.x, ln = tid & 63, wv = tid >> 6;
  if (tid == 0) carry = 0;
  __syncthreads();
  for (int base = 0; base < NBK; base += 256) {
    int i = base + tid;
    int x = (i < NBK) ? gcnt[i] : 0;
    int v = x;
#pragma unroll
    for (int d = 1; d < 64; d <<= 1) {
      int t = __shfl_up(v, d);
      if (ln >= d) v += t;
    }
    if (ln == 63) ws[wv] = v;
    __syncthreads();
    int w0 = ws[0], w1 = ws[1], w2 = ws[2], w3 = ws[3];
    int woff = (wv == 0) ? 0 : (wv == 1) ? w0 : (wv == 2) ? w0 + w1 : w0 + w1 + w2;
    int excl = carry + woff + v - x;
    if (i < NBK) { boff[i] = excl; gcursor[i] = excl; }
    int tot = w0 + w1 + w2 + w3;
    __syncthreads();
    if (tid == 0) carry += tot;
    __syncthreads();
  }
  if (threadIdx.x == 0) boff[NBK] = NE;
}

// ---------------------------------------------------------------------------
// bucket scatter: block-local LDS counts -> per-bucket range reserve ->
// packed (src<<6 | dstLow) appended. Low write amplification.
// ---------------------------------------------------------------------------
__global__ __launch_bounds__(512) void bscatter(const int* __restrict__ src,
    const int* __restrict__ dst, int* __restrict__ gcursor,
    uint* __restrict__ packed) {
  __shared__ int lcnt[NBK];
  __shared__ int lbase[NBK];
  __shared__ int lrank[NBK];
  const int tid = threadIdx.x;
  const int PER = (NE + 255) / 256;   // 3125
  const int e0 = blockIdx.x * PER;
  const int e1 = min(NE, e0 + PER);
  for (int i = tid; i < NBK; i += 512) { lcnt[i] = 0; lrank[i] = 0; }
  __syncthreads();
  for (int e = e0 + tid; e < e1; e += 512) atomicAdd(&lcnt[dst[e] >> 6], 1);
  __syncthreads();
  for (int i = tid; i < NBK; i += 512) {
    int c = lcnt[i];
    lbase[i] = c ? atomicAdd(&gcursor[i], c) : 0;
  }
  __syncthreads();
  for (int e = e0 + tid; e < e1; e += 512) {
    int d = dst[e], b = d >> 6;
    int r = atomicAdd(&lrank[b], 1);
    packed[lbase[b] + r] = ((uint)src[e] << 6) | (uint)(d & 63);
  }
}

// ---------------------------------------------------------------------------
// per-bucket counting sort: packed (bucket-grouped) -> node-sorted ssrc +
// exact per-node CSR (row_off, deg). One block per bucket.
// ---------------------------------------------------------------------------
__global__ __launch_bounds__(256) void bsort(const uint* __restrict__ packed,
    const int* __restrict__ boff, int* __restrict__ ssrc,
    int* __restrict__ row_off, int* __restrict__ deg) {
  __shared__ int cnt[64], base[64], rank[64];
  const int b = blockIdx.x, tid = threadIdx.x;
  const int e0 = boff[b], e1 = boff[b + 1];
  if (tid < 64) { cnt[tid] = 0; rank[tid] = 0; }
  __syncthreads();
  for (int e = e0 + tid; e < e1; e += 256)
    atomicAdd(&cnt[packed[e] & 63], 1);
  __syncthreads();
  if (tid < 64) {                      // wave 0: scan 64 counts
    int x = cnt[tid];
    int v = x;
#pragma unroll
    for (int d = 1; d < 64; d <<= 1) {
      int t = __shfl_up(v, d);
      if (tid >= d) v += t;
    }
    base[tid] = v - x;
    int node = b * 64 + tid;
    if (node < NN) { row_off[node] = e0 + v - x; deg[node] = x; }
  }
  __syncthreads();
  for (int e = e0 + tid; e < e1; e += 256) {
    uint p = packed[e];
    int dl = p & 63;
    int r = atomicAdd(&rank[dl], 1);
    ssrc[e0 + base[dl] + r] = (int)(p >> 6);
  }
}

// ---------------------------------------------------------------------------
// MFMA GEMM (MODE 0 only): feat = h(f32,staged-cvt) @ Wfc^T, fused el/er.
// 64-row tiles, 4 waves (2x2), wave = 32x64 (acc[2][4]).
// A-tile in LDS (XOR-swizzled); B fragments direct from global.
// ---------------------------------------------------------------------------
__global__ __launch_bounds__(256) void mgemm0(
    const float* __restrict__ A0f, const ushort* __restrict__ Wt,
    const float* __restrict__ al, const float* __restrict__ ar,
    float* __restrict__ el, float* __restrict__ er,
    ushort* __restrict__ outb, int M)
{
  __shared__ char As[64 * 256];
  const int tid  = threadIdx.x;
  const int row0 = blockIdx.x * 64;

#pragma unroll
  for (int c = 0; c < 4; c++) {
    int idx = tid + c * 256;
    int r  = idx >> 4;
    int kc = idx & 15;
    int sw = ((kc * 16) ^ ((r & 7) << 4));
    uint4 va = make_uint4(0u, 0u, 0u, 0u);
    if (row0 + r < M) va = cvt8(A0f + (size_t)(row0 + r) * 128 + kc * 8);
    *(uint4*)(As + r * 256 + sw) = va;
  }
  __syncthreads();

  const int ln = tid & 63, wv = tid >> 6;
  const int wm = wv >> 1, wn = wv & 1;
  const int lr = ln & 15, lk = ln >> 4;

  f32x4 acc[2][4] = {};
#pragma unroll
  for (int ks = 0; ks < 4; ks++) {
    int k2 = ks * 64 + lk * 16;
    bf16x8 af[2], bfr[4];
#pragma unroll
    for (int mt = 0; mt < 2; mt++) {
      int arr = wm * 32 + mt * 16 + lr;
      af[mt] = *(const bf16x8*)(As + arr * 256 + (k2 ^ ((arr & 7) << 4)));
    }
#pragma unroll
    for (int nt = 0; nt < 4; nt++) {
      int bn = wn * 64 + nt * 16 + lr;
      bfr[nt] = *(const bf16x8*)(Wt + (size_t)bn * 128 + ks * 32 + lk * 8);
    }
#pragma unroll
    for (int mt = 0; mt < 2; mt++)
#pragma unroll
      for (int nt = 0; nt < 4; nt++)
        acc[mt][nt] = __builtin_amdgcn_mfma_f32_16x16x32_bf16(
            af[mt], bfr[nt], acc[mt][nt], 0, 0, 0);
  }

  float alv[4], arv[4];
#pragma unroll
  for (int nt = 0; nt < 4; nt++) {
    int col = wn * 64 + nt * 16 + lr;
    alv[nt] = al[col]; arv[nt] = ar[col];
  }
#pragma unroll
  for (int mt = 0; mt < 2; mt++) {
#pragma unroll
    for (int r = 0; r < 4; r++) {
      int row = row0 + wm * 32 + mt * 16 + lk * 4 + r;
      float pl0 = acc[mt][0][r] * alv[0] + acc[mt][1][r] * alv[1];
      float pl1 = acc[mt][2][r] * alv[2] + acc[mt][3][r] * alv[3];
      float pr0 = acc[mt][0][r] * arv[0] + acc[mt][1][r] * arv[1];
      float pr1 = acc[mt][2][r] * arv[2] + acc[mt][3][r] * arv[3];
#pragma unroll
      for (int m2 = 1; m2 < 16; m2 <<= 1) {
        pl0 += __shfl_xor(pl0, m2); pl1 += __shfl_xor(pl1, m2);
        pr0 += __shfl_xor(pr0, m2); pr1 += __shfl_xor(pr1, m2);
      }
      if (row < M) {
#pragma unroll
        for (int nt = 0; nt < 4; nt++)
          outb[(size_t)row * 128 + wn * 64 + nt * 16 + lr] = f2b(acc[mt][nt][r]);
        if (lr == 0) {
          *(float2*)(el + row * 4 + 2 * wn) = make_float2(pl0, pl1);
          *(float2*)(er + row * 4 + 2 * wn) = make_float2(pr0, pr1);
        }
      }
    }
  }
}

// ---------------------------------------------------------------------------
// Fused projection + gate kernel:
//   hp = hgat @ Wpr + b_proj          (MFMA1, f32 kept in acc1)
//   v  = [hp_bf16 | ctx_bf16] @ Wgt + b_gate   (MFMA2, K=256 via LDS Hs)
//   out = ctx + sigmoid(v) * (hp - ctx)
// C-layouts of MFMA1/MFMA2 are identical -> blend's hp comes from acc1
// at the same (row,col); ctx read back from Hs. LDS 48KB -> 3 blocks/CU.
// ---------------------------------------------------------------------------
__global__ __launch_bounds__(256) void pg_k(
    const ushort* __restrict__ hgatb, const float* __restrict__ ctx,
    const ushort* __restrict__ Tpr, const ushort* __restrict__ Tgt,
    const float* __restrict__ b_proj, const float* __restrict__ b_gate,
    float* __restrict__ out, int M)
{
  __shared__ char As[64 * 256];   // hgat tile (16KB)
  __shared__ char Hs[64 * 512];   // [hp | ctx] bf16 (32KB)
  const int tid  = threadIdx.x;
  const int row0 = blockIdx.x * 64;

  // stage hgat -> As
#pragma unroll
  for (int c = 0; c < 4; c++) {
    int idx = tid + c * 256;
    int r = idx >> 4, kc = idx & 15;
    int sw = (kc * 16) ^ ((r & 7) << 4);
    uint4 va = make_uint4(0u, 0u, 0u, 0u);
    if (row0 + r < M) va = *(const uint4*)(hgatb + (size_t)(row0 + r) * 128 + kc * 8);
    *(uint4*)(As + r * 256 + sw) = va;
  }
  // stage ctx (f32 -> bf16) -> Hs second half (bytes 256..511 of each row)
#pragma unroll
  for (int c = 0; c < 4; c++) {
    int idx = tid + c * 256;
    int r = idx >> 4, kc = (idx & 15) + 16;
    int sw = (kc * 16) ^ ((r & 7) << 4);
    uint4 va = make_uint4(0u, 0u, 0u, 0u);
    if (row0 + r < M) va = cvt8(ctx + (size_t)(row0 + r) * 128 + (kc - 16) * 8);
    *(uint4*)(Hs + r * 512 + sw) = va;
  }
  __syncthreads();

  const int ln = tid & 63, wv = tid >> 6;
  const int wm = wv >> 1, wn = wv & 1;
  const int lr = ln & 15, lk = ln >> 4;

  float bpv[4], bgv[4];
#pragma unroll
  for (int nt = 0; nt < 4; nt++) {
    int col = wn * 64 + nt * 16 + lr;
    bpv[nt] = b_proj[col]; bgv[nt] = b_gate[col];
  }

  // MFMA1: hp = hgat @ Wpr
  f32x4 acc1[2][4] = {};
#pragma unroll
  for (int ks = 0; ks < 4; ks++) {
    int k2 = ks * 64 + lk * 16;
    bf16x8 af[2], bfr[4];
#pragma unroll
    for (int mt = 0; mt < 2; mt++) {
      int arr = wm * 32 + mt * 16 + lr;
      af[mt] = *(const bf16x8*)(As + arr * 256 + (k2 ^ ((arr & 7) << 4)));
    }
#pragma unroll
    for (int nt = 0; nt < 4; nt++) {
      int bn = wn * 64 + nt * 16 + lr;
      bfr[nt] = *(const bf16x8*)(Tpr + (size_t)bn * 128 + ks * 32 + lk * 8);
    }
#pragma unroll
    for (int mt = 0; mt < 2; mt++)
#pragma unroll
      for (int nt = 0; nt < 4; nt++)
        acc1[mt][nt] = __builtin_amdgcn_mfma_f32_16x16x32_bf16(
            af[mt], bfr[nt], acc1[mt][nt], 0, 0, 0);
  }
  // + b_proj; write hp bf16 into Hs first half
#pragma unroll
  for (int mt = 0; mt < 2; mt++) {
#pragma unroll
    for (int r = 0; r < 4; r++) {
      int lrow = wm * 32 + mt * 16 + lk * 4 + r;
#pragma unroll
      for (int nt = 0; nt < 4; nt++) {
        int col = wn * 64 + nt * 16 + lr;
        acc1[mt][nt][r] += bpv[nt];
        *(ushort*)(Hs + lrow * 512 + ((2 * col) ^ ((lrow & 7) << 4))) =
            f2b(acc1[mt][nt][r]);
      }
    }
  }
  __syncthreads();

  // MFMA2: v = [hp|ctx] @ Wgt (K=256)
  f32x4 acc2[2][4] = {};
#pragma unroll
  for (int ks = 0; ks < 8; ks++) {
    int k2 = ks * 64 + lk * 16;
    bf16x8 af[2], bfr[4];
#pragma unroll
    for (int mt = 0; mt < 2; mt++) {
      int arr = wm * 32 + mt * 16 + lr;
      af[mt] = *(const bf16x8*)(Hs + arr * 512 + (k2 ^ ((arr & 7) << 4)));
    }
#pragma unroll
    for (int nt = 0; nt < 4; nt++) {
      int bn = wn * 64 + nt * 16 + lr;
      bfr[nt] = *(const bf16x8*)(Tgt + (size_t)bn * 256 + ks * 32 + lk * 8);
    }
#pragma unroll
    for (int mt = 0; mt < 2; mt++)
#pragma unroll
      for (int nt = 0; nt < 4; nt++)
        acc2[mt][nt] = __builtin_amdgcn_mfma_f32_16x16x32_bf16(
            af[mt], bfr[nt], acc2[mt][nt], 0, 0, 0);
  }

  // epilogue: gate blend (hp f32 from acc1, ctx from Hs)
#pragma unroll
  for (int mt = 0; mt < 2; mt++) {
#pragma unroll
    for (int r = 0; r < 4; r++) {
      int lrow = wm * 32 + mt * 16 + lk * 4 + r;
      int row  = row0 + lrow;
      if (row >= M) continue;
#pragma unroll
      for (int nt = 0; nt < 4; nt++) {
        int col = wn * 64 + nt * 16 + lr;
        float hp = acc1[mt][nt][r];
        float cx = b2f(*(const ushort*)(Hs + lrow * 512 +
                        ((2 * col + 256) ^ ((lrow & 7) << 4))));
        float g = 1.f / (1.f + __expf(-(acc2[mt][nt][r] + bgv[nt])));
        out[(size_t)row * 128 + col] = cx + g * (hp - cx);
      }
    }
  }
}

// ---------------------------------------------------------------------------
// Aggregation: one wave per dst node; lane covers features (2l,2l+1) bf16;
// register accumulation; 4-way edge unroll for gather MLP.
// ---------------------------------------------------------------------------
__global__ __launch_bounds__(256) void agg_k(
    const ushort* __restrict__ featb, const float* __restrict__ el,
    const float* __restrict__ er, const int* __restrict__ deg,
    const int* __restrict__ row_off, const int* __restrict__ ssrc,
    const float* __restrict__ bias, ushort* __restrict__ hgatb)
{
  const int wid = (blockIdx.x * 256 + threadIdx.x) >> 6;
  if (wid >= NN) return;
  const int ln = threadIdx.x & 63;
  const int head = ln >> 4;
  const int cnt = deg[wid];
  const int start = row_off[wid];
  const float erh = er[wid * 4 + head];
  const uint* f2 = (const uint*)featb;

  float ax0 = 0.f, ay0 = 0.f, dn0 = 0.f;
  float ax1 = 0.f, ay1 = 0.f, dn1 = 0.f;
  for (int base = 0; base < cnt; base += 64) {
    int m = min(64, cnt - base);
    int sv = (ln < m) ? ssrc[start + base + ln] : 0;
    int i = 0;
    for (; i + 3 < m; i += 4) {
      int s0 = __shfl(sv, i),     s1 = __shfl(sv, i + 1);
      int s2 = __shfl(sv, i + 2), s3 = __shfl(sv, i + 3);
      float e0 = el[s0 * 4 + head], e1 = el[s1 * 4 + head];
      float e2 = el[s2 * 4 + head], e3 = el[s3 * 4 + head];
      uint u0 = f2[(size_t)s0 * 64 + ln], u1 = f2[(size_t)s1 * 64 + ln];
      uint u2 = f2[(size_t)s2 * 64 + ln], u3 = f2[(size_t)s3 * 64 + ln];
      e0 += erh; e1 += erh; e2 += erh; e3 += erh;
      e0 = e0 > 0.f ? e0 : 0.2f * e0;
      e1 = e1 > 0.f ? e1 : 0.2f * e1;
      e2 = e2 > 0.f ? e2 : 0.2f * e2;
      e3 = e3 > 0.f ? e3 : 0.2f * e3;
      float a0 = __expf(e0), a1 = __expf(e1);
      float a2 = __expf(e2), a3 = __expf(e3);
      ax0 = fmaf(a0, b2f((ushort)(u0 & 0xffff)), ax0);
      ay0 = fmaf(a0, b2f((ushort)(u0 >> 16)), ay0);
      ax1 = fmaf(a1, b2f((ushort)(u1 & 0xffff)), ax1);
      ay1 = fmaf(a1, b2f((ushort)(u1 >> 16)), ay1);
      ax0 = fmaf(a2, b2f((ushort)(u2 & 0xffff)), ax0);
      ay0 = fmaf(a2, b2f((ushort)(u2 >> 16)), ay0);
      ax1 = fmaf(a3, b2f((ushort)(u3 & 0xffff)), ax1);
      ay1 = fmaf(a3, b2f((ushort)(u3 >> 16)), ay1);
      dn0 += a0 + a2;
      dn1 += a1 + a3;
    }
    for (; i < m; i++) {
      int s0 = __shfl(sv, i);
      float e0 = el[s0 * 4 + head] + erh;
      uint u0 = f2[(size_t)s0 * 64 + ln];
      e0 = e0 > 0.f ? e0 : 0.2f * e0;
      float a0 = __expf(e0);
      ax0 = fmaf(a0, b2f((ushort)(u0 & 0xffff)), ax0);
      ay0 = fmaf(a0, b2f((ushort)(u0 >> 16)), ay0);
      dn0 += a0;
    }
  }
  float dn = dn0 + dn1;
  float inv = (cnt > 0) ? (1.0f / dn) : 0.0f;
  float2 bv = ((const float2*)bias)[ln];
  float rx = fmaf(ax0 + ax1, inv, bv.x);
  float ry = fmaf(ay0 + ay1, inv, bv.y);
  rx = rx > 0.f ? rx : expm1f(rx);
  ry = ry > 0.f ? ry : expm1f(ry);
  uint o = (uint)f2b(rx) | ((uint)f2b(ry) << 16);
  ((uint*)hgatb)[(size_t)wid * 64 + ln] = o;
}

// ---------------------------------------------------------------------------
extern "C" void kernel_launch(void* const* d_in, const int* in_sizes, int n_in,
                              void* d_out, int out_size, void* d_ws, size_t ws_size,
                              hipStream_t stream) {
  const float* h        = (const float*)d_in[0];
  const int*   src      = (const int*)d_in[1];
  const int*   dst      = (const int*)d_in[2];
  const float* ctx      = (const float*)d_in[3];
  const float* W_fc     = (const float*)d_in[4];
  const float* attn_l   = (const float*)d_in[5];
  const float* attn_r   = (const float*)d_in[6];
  const float* bias_gat = (const float*)d_in[7];
  const float* W_proj   = (const float*)d_in[8];
  const float* b_proj   = (const float*)d_in[9];
  const float* W_gate   = (const float*)d_in[10];
  const float* b_gate   = (const float*)d_in[11];
  float* out = (float*)d_out;

  char* ws = (char*)d_ws;
  size_t off = 0;
  auto take = [&](size_t bytes) -> void* {
    void* p = ws + off;
    off += (bytes + 255) & ~(size_t)255;
    return p;
  };
  ushort* featb  = (ushort*)take((size_t)NN * 128 * 2);
  ushort* hgatb  = (ushort*)take((size_t)NN * 128 * 2);
  float*  el     = (float*)take((size_t)NN * 4 * 4);
  float*  er     = (float*)take((size_t)NN * 4 * 4);
  int*    gcnt   = (int*)take((size_t)NBK * 4);
  int*    boff   = (int*)take((size_t)(NBK + 1) * 4);
  int*    gcur   = (int*)take((size_t)NBK * 4);
  uint*   packed = (uint*)take((size_t)NE * 4);
  int*    ssrc   = (int*)take((size_t)NE * 4);
  int*    row_off= (int*)take((size_t)NN * 4);
  int*    deg    = (int*)take((size_t)NN * 4);
  ushort* Tfc    = (ushort*)take(16384 * 2);
  ushort* Tpr    = (ushort*)take(16384 * 2);
  ushort* Tgt    = (ushort*)take(32768 * 2);

  hipMemsetAsync(gcnt, 0, (size_t)NBK * 4, stream);

  const int gb = (NN + 63) / 64;         // 782
  const size_t smem4 = 64 * 256;         // 16 KB (A-tile only)

  cvt_w<<<256, 256, 0, stream>>>(W_fc, W_proj, W_gate, Tfc, Tpr, Tgt);
  // bucket partition + per-bucket counting sort -> node-sorted CSR
  bhist<<<256, 512, 0, stream>>>(dst, gcnt);
  bscan<<<1, 256, 0, stream>>>(gcnt, boff, gcur);
  bscatter<<<256, 512, 0, stream>>>(src, dst, gcur, packed);
  bsort<<<NBK, 256, 0, stream>>>(packed, boff, ssrc, row_off, deg);
  // feat = h @ W_fc (f32 in, bf16 out) + fused el/er
  mgemm0<<<gb, 256, smem4, stream>>>(h, Tfc, attn_l, attn_r, el, er, featb, NN);
  // edge-softmax aggregation -> h_gat (bf16), register accumulation
  agg_k<<<12500, 256, 0, stream>>>(featb, el, er, deg, row_off, ssrc,
                                   bias_gat, hgatb);
  // fused: hp = hgat@Wpr + b; out = blend(sigmoid([hp|ctx]@Wgt + bg), hp, ctx)
  pg_k<<<gb, 256, 0, stream>>>(hgatb, ctx, Tpr, Tgt, b_proj, b_gate, out, NN);
}